// Round 3
// baseline (98.379 us; speedup 1.0000x reference)
//
#include <hip/hip_runtime.h>
#include <stdint.h>

// BayesianLinear: out = x @ (mu_w + exp(ls_w)*eps_w)^T + (mu_b + exp(ls_b)*eps_b)
// M=1024, N=4096, K=4096. fp32 in/out, bf16-tolerance harness => bf16 MFMA.
//
// R3: (a) single fused prep kernel, 4 triplets/thread w/ compile-time offsets
//     (12 loads in flight, was 3 -> latency-bound at 1.76 TB/s);
//     (b) gemm: double-buffered LDS 2-phase pipeline (stage t+1 before compute t,
//     ONE barrier per k-step; the vmcnt(0) drain is covered by ds_read+MFMA).
//     Geometry/swizzle/epilogue identical to passing R2 kernel.

#define IN_F  4096
#define OUT_F 4096
#define BATCH 1024

typedef unsigned short u16;
typedef __attribute__((ext_vector_type(8))) short bf16x8;
typedef __attribute__((ext_vector_type(4))) float f32x4;

__device__ __forceinline__ u16 f2bf(float f) {
  uint32_t u = __float_as_uint(f);
  return (u16)((u + 0x7FFFu + ((u >> 16) & 1u)) >> 16);
}

__device__ __forceinline__ void gload_lds16(const void* g, void* l) {
  __builtin_amdgcn_global_load_lds(
      (const __attribute__((address_space(1))) void*)g,
      (__attribute__((address_space(3))) void*)l, 16, 0, 0);
}

// ---------------- fused prep kernel ----------------
// blocks [0,4096): W (4096*256*4 = 16.78M float4-triplets -> bf16)
// blocks [4096,5120): x -> bf16    blocks [5120,5136): bias

#define PREP_W_BLOCKS 4096
#define PREP_X_BLOCKS 1024
#define PREP_GRID (PREP_W_BLOCKS + PREP_X_BLOCKS + 16)

__global__ void __launch_bounds__(256) prep_kernel(
    const float* __restrict__ mu_w, const float* __restrict__ ls_w,
    const float* __restrict__ eps_w, u16* __restrict__ wq,
    const float* __restrict__ x, u16* __restrict__ xq,
    const float* __restrict__ mu_b, const float* __restrict__ ls_b,
    const float* __restrict__ eps_b, float* __restrict__ bq) {
  const int bid = blockIdx.x;
  const int tid = threadIdx.x;
  if (bid < PREP_W_BLOCKS) {
    const int64_t base = (int64_t)bid * 1024 + tid;
    float4 m[4], s[4], e[4];
#pragma unroll
    for (int j = 0; j < 4; j++) {
      m[j] = ((const float4*)mu_w)[base + j * 256];
      s[j] = ((const float4*)ls_w)[base + j * 256];
      e[j] = ((const float4*)eps_w)[base + j * 256];
    }
#pragma unroll
    for (int j = 0; j < 4; j++) {
      ushort4 o;
      o.x = f2bf(fmaf(__expf(s[j].x), e[j].x, m[j].x));
      o.y = f2bf(fmaf(__expf(s[j].y), e[j].y, m[j].y));
      o.z = f2bf(fmaf(__expf(s[j].z), e[j].z, m[j].z));
      o.w = f2bf(fmaf(__expf(s[j].w), e[j].w, m[j].w));
      ((ushort4*)wq)[base + j * 256] = o;
    }
  } else if (bid < PREP_W_BLOCKS + PREP_X_BLOCKS) {
    const int64_t base = (int64_t)(bid - PREP_W_BLOCKS) * 1024 + tid;
    float4 v[4];
#pragma unroll
    for (int j = 0; j < 4; j++) v[j] = ((const float4*)x)[base + j * 256];
#pragma unroll
    for (int j = 0; j < 4; j++) {
      ushort4 o;
      o.x = f2bf(v[j].x); o.y = f2bf(v[j].y); o.z = f2bf(v[j].z); o.w = f2bf(v[j].w);
      ((ushort4*)xq)[base + j * 256] = o;
    }
  } else {
    const int i = (bid - PREP_W_BLOCKS - PREP_X_BLOCKS) * 256 + tid;
    if (i < OUT_F) bq[i] = fmaf(__expf(ls_b[i]), eps_b[i], mu_b[i]);
  }
}

// ---------------- GEMM (NT layout: C[m][n] = sum_k X[m][k]*W[n][k] + bias[n]) ----------------

#define BM 64
#define BN 128
#define BK 64
#define NBX (OUT_F / BN)   // 32 col-blocks x 16 row-blocks = 512 workgroups (2/CU)
#define NTILES (IN_F / BK) // 64 k-steps

__global__ void __launch_bounds__(256) gemm_kernel(
    const u16* __restrict__ X, const u16* __restrict__ W,
    const float* __restrict__ bias, float* __restrict__ out) {
  __shared__ u16 ldsA[2][BM * BK];  // 2 x 8 KB
  __shared__ u16 ldsB[2][BN * BK];  // 2 x 16 KB  (48 KB total)

  const int tid = threadIdx.x;
  const int lane = tid & 63;
  const int wave = tid >> 6;
  const int wr = wave >> 1;              // 0..1 (32 rows each)
  const int wc = wave & 1;               // 0..1 (64 cols each)
  const int bx = blockIdx.x & (NBX - 1); // B-panel sharers land on same XCD (32 % 8 == 0)
  const int by = blockIdx.x / NBX;

  const u16* Abase = X + (int64_t)by * BM * IN_F;
  const u16* Bbase = W + (int64_t)bx * BN * IN_F;

  // staging decode: chunk c -> row = c>>3, phys slot = c&7; LDS linear at c*16B,
  // global src uses slot sp^(row&7) so a reader XORing the same mask is conflict-free.
  int offA[2], ldA[2], offB[4], ldB[4];
#pragma unroll
  for (int j = 0; j < 2; j++) {
    const int c = tid + j * 256, r = c >> 3, sp = c & 7;
    offA[j] = r * IN_F + ((sp ^ (r & 7)) * 8);
    ldA[j] = c * 8;
  }
#pragma unroll
  for (int j = 0; j < 4; j++) {
    const int c = tid + j * 256, r = c >> 3, sp = c & 7;
    offB[j] = r * IN_F + ((sp ^ (r & 7)) * 8);
    ldB[j] = c * 8;
  }

  const int rl = lane & 15;
  const int lk = lane >> 4;

  // prologue: stage tile 0 into buffer 0
#pragma unroll
  for (int j = 0; j < 2; j++) gload_lds16(Abase + offA[j], &ldsA[0][ldA[j]]);
#pragma unroll
  for (int j = 0; j < 4; j++) gload_lds16(Bbase + offB[j], &ldsB[0][ldB[j]]);
  __syncthreads();  // compiler drains vmcnt(0): tile 0 ready

  f32x4 acc[2][4] = {};

  for (int t = 0; t < NTILES; ++t) {
    const int cur = t & 1;
    const u16* lA = ldsA[cur];
    const u16* lB = ldsB[cur];
    if (t + 1 < NTILES) {  // stage next tile into other buffer (covered by compute below)
      const int k0 = (t + 1) * BK;
#pragma unroll
      for (int j = 0; j < 2; j++) gload_lds16(Abase + offA[j] + k0, &ldsA[cur ^ 1][ldA[j]]);
#pragma unroll
      for (int j = 0; j < 4; j++) gload_lds16(Bbase + offB[j] + k0, &ldsB[cur ^ 1][ldB[j]]);
    }

    bf16x8 af[2][2], bfv[2][4];
#pragma unroll
    for (int kk = 0; kk < 2; kk++) {
      const int slot = kk * 4 + lk;
#pragma unroll
      for (int m = 0; m < 2; m++) {
        const int R = wr * 32 + m * 16 + rl;
        af[kk][m] = *(const bf16x8*)(lA + R * BK + ((slot ^ (R & 7)) * 8));
      }
#pragma unroll
      for (int n = 0; n < 4; n++) {
        const int R = wc * 64 + n * 16 + rl;
        bfv[kk][n] = *(const bf16x8*)(lB + R * BK + ((slot ^ (R & 7)) * 8));
      }
    }
#pragma unroll
    for (int kk = 0; kk < 2; kk++)
#pragma unroll
      for (int m = 0; m < 2; m++)
#pragma unroll
        for (int n = 0; n < 4; n++)
          acc[m][n] = __builtin_amdgcn_mfma_f32_16x16x32_bf16(af[kk][m], bfv[kk][n], acc[m][n], 0, 0, 0);

    __syncthreads();  // waits my next-tile loads (vmcnt0) + everyone's reads of cur
  }

  // epilogue: C/D layout col = lane&15, row = (lane>>4)*4 + reg  [m89-verified]
  const int gr0 = by * BM + wr * 32;
  const int gc0 = bx * BN + wc * 64;
  const int rh = (lane >> 4) * 4;
  float bv[4];
#pragma unroll
  for (int n = 0; n < 4; n++) bv[n] = bias[gc0 + n * 16 + rl];
#pragma unroll
  for (int m = 0; m < 2; m++) {
#pragma unroll
    for (int n = 0; n < 4; n++) {
      const int col = gc0 + n * 16 + rl;
#pragma unroll
      for (int j = 0; j < 4; j++)
        out[(int64_t)(gr0 + m * 16 + rh + j) * OUT_F + col] = acc[m][n][j] + bv[n];
    }
  }
}

// ---------------- launch ----------------

extern "C" void kernel_launch(void* const* d_in, const int* in_sizes, int n_in,
                              void* d_out, int out_size, void* d_ws, size_t ws_size,
                              hipStream_t stream) {
  const float* x     = (const float*)d_in[0];
  const float* eps_w = (const float*)d_in[1];
  const float* eps_b = (const float*)d_in[2];
  const float* mu_w  = (const float*)d_in[3];
  const float* ls_w  = (const float*)d_in[4];
  const float* mu_b  = (const float*)d_in[5];
  const float* ls_b  = (const float*)d_in[6];
  float* out = (float*)d_out;

  u16* Wq = (u16*)d_ws;                              // 32 MB
  u16* Xq = Wq + (size_t)OUT_F * IN_F;               //  8 MB
  float* bq = (float*)(Xq + (size_t)BATCH * IN_F);   // 16 KB

  prep_kernel<<<PREP_GRID, 256, 0, stream>>>(mu_w, ls_w, eps_w, Wq,
                                             x, Xq, mu_b, ls_b, eps_b, bq);
  gemm_kernel<<<(BATCH / BM) * NBX, 256, 0, stream>>>(Xq, Wq, bq, out);
}

// Round 4
// 82.702 us; speedup vs baseline: 1.1896x; 1.1896x over previous
//
#include <hip/hip_runtime.h>
#include <stdint.h>

// BayesianLinear: out = x @ (mu_w + exp(ls_w)*eps_w)^T + (mu_b + exp(ls_b)*eps_b)
// M=1024, N=4096, K=4096. fp32 in/out, bf16-tolerance harness => bf16 MFMA.
//
// R4: gemm k-loop -> counted-vmcnt pipeline (T3/T4-lite): 3-deep LDS buffers,
// stage 2 tiles ahead, raw s_barrier + s_waitcnt vmcnt(6) so prefetch loads
// stay in flight ACROSS the barrier (R3's __syncthreads forced a vmcnt(0)
// drain per k-step = the exposed stall). Geometry/swizzle/epilogue/prep frozen.

#define IN_F  4096
#define OUT_F 4096
#define BATCH 1024

typedef unsigned short u16;
typedef __attribute__((ext_vector_type(8))) short bf16x8;
typedef __attribute__((ext_vector_type(4))) float f32x4;

__device__ __forceinline__ u16 f2bf(float f) {
  uint32_t u = __float_as_uint(f);
  return (u16)((u + 0x7FFFu + ((u >> 16) & 1u)) >> 16);
}

__device__ __forceinline__ void gload_lds16(const void* g, void* l) {
  __builtin_amdgcn_global_load_lds(
      (const __attribute__((address_space(1))) void*)g,
      (__attribute__((address_space(3))) void*)l, 16, 0, 0);
}

// ---------------- fused prep kernel (unchanged from R3) ----------------

#define PREP_W_BLOCKS 4096
#define PREP_X_BLOCKS 1024
#define PREP_GRID (PREP_W_BLOCKS + PREP_X_BLOCKS + 16)

__global__ void __launch_bounds__(256) prep_kernel(
    const float* __restrict__ mu_w, const float* __restrict__ ls_w,
    const float* __restrict__ eps_w, u16* __restrict__ wq,
    const float* __restrict__ x, u16* __restrict__ xq,
    const float* __restrict__ mu_b, const float* __restrict__ ls_b,
    const float* __restrict__ eps_b, float* __restrict__ bq) {
  const int bid = blockIdx.x;
  const int tid = threadIdx.x;
  if (bid < PREP_W_BLOCKS) {
    const int64_t base = (int64_t)bid * 1024 + tid;
    float4 m[4], s[4], e[4];
#pragma unroll
    for (int j = 0; j < 4; j++) {
      m[j] = ((const float4*)mu_w)[base + j * 256];
      s[j] = ((const float4*)ls_w)[base + j * 256];
      e[j] = ((const float4*)eps_w)[base + j * 256];
    }
#pragma unroll
    for (int j = 0; j < 4; j++) {
      ushort4 o;
      o.x = f2bf(fmaf(__expf(s[j].x), e[j].x, m[j].x));
      o.y = f2bf(fmaf(__expf(s[j].y), e[j].y, m[j].y));
      o.z = f2bf(fmaf(__expf(s[j].z), e[j].z, m[j].z));
      o.w = f2bf(fmaf(__expf(s[j].w), e[j].w, m[j].w));
      ((ushort4*)wq)[base + j * 256] = o;
    }
  } else if (bid < PREP_W_BLOCKS + PREP_X_BLOCKS) {
    const int64_t base = (int64_t)(bid - PREP_W_BLOCKS) * 1024 + tid;
    float4 v[4];
#pragma unroll
    for (int j = 0; j < 4; j++) v[j] = ((const float4*)x)[base + j * 256];
#pragma unroll
    for (int j = 0; j < 4; j++) {
      ushort4 o;
      o.x = f2bf(v[j].x); o.y = f2bf(v[j].y); o.z = f2bf(v[j].z); o.w = f2bf(v[j].w);
      ((ushort4*)xq)[base + j * 256] = o;
    }
  } else {
    const int i = (bid - PREP_W_BLOCKS - PREP_X_BLOCKS) * 256 + tid;
    if (i < OUT_F) bq[i] = fmaf(__expf(ls_b[i]), eps_b[i], mu_b[i]);
  }
}

// ---------------- GEMM (NT: C[m][n] = sum_k X[m][k]*W[n][k] + bias[n]) ----------------

#define BM 64
#define BN 128
#define BK 64
#define NBX (OUT_F / BN)   // 32 x 16 = 512 workgroups (2/CU)
#define NTILES (IN_F / BK) // 64 k-steps

__global__ void __launch_bounds__(256) gemm_kernel(
    const u16* __restrict__ X, const u16* __restrict__ W,
    const float* __restrict__ bias, float* __restrict__ out) {
  __shared__ u16 ldsA[3][BM * BK];  // 3 x 8 KB
  __shared__ u16 ldsB[3][BN * BK];  // 3 x 16 KB (72 KB total -> 2 blocks/CU)

  const int tid = threadIdx.x;
  const int lane = tid & 63;
  const int wave = tid >> 6;
  const int wr = wave >> 1;              // 0..1 (32 rows each)
  const int wc = wave & 1;               // 0..1 (64 cols each)
  const int bx = blockIdx.x & (NBX - 1); // B-panel sharers on same XCD (32%8==0)
  const int by = blockIdx.x / NBX;

  const u16* Abase = X + (int64_t)by * BM * IN_F;
  const u16* Bbase = W + (int64_t)bx * BN * IN_F;

  // staging decode: chunk c -> row = c>>3, phys slot = c&7; LDS linear at c*16B,
  // global src uses slot sp^(row&7) so a reader XORing the same mask is conflict-free.
  int offA[2], ldA[2], offB[4], ldB[4];
#pragma unroll
  for (int j = 0; j < 2; j++) {
    const int c = tid + j * 256, r = c >> 3, sp = c & 7;
    offA[j] = r * IN_F + ((sp ^ (r & 7)) * 8);
    ldA[j] = c * 8;
  }
#pragma unroll
  for (int j = 0; j < 4; j++) {
    const int c = tid + j * 256, r = c >> 3, sp = c & 7;
    offB[j] = r * IN_F + ((sp ^ (r & 7)) * 8);
    ldB[j] = c * 8;
  }

  const int rl = lane & 15;
  const int lk = lane >> 4;

  // prologue: stage tiles 0 and 1 (6 gload_lds each)
#pragma unroll
  for (int j = 0; j < 2; j++) gload_lds16(Abase + offA[j], &ldsA[0][ldA[j]]);
#pragma unroll
  for (int j = 0; j < 4; j++) gload_lds16(Bbase + offB[j], &ldsB[0][ldB[j]]);
#pragma unroll
  for (int j = 0; j < 2; j++) gload_lds16(Abase + offA[j] + BK, &ldsA[1][ldA[j]]);
#pragma unroll
  for (int j = 0; j < 4; j++) gload_lds16(Bbase + offB[j] + BK, &ldsB[1][ldB[j]]);

  f32x4 acc[2][4] = {};

  for (int t = 0; t < NTILES; ++t) {
    // wait tile t's 6 loads (oldest) while tile t+1's 6 stay in flight
    if (t < NTILES - 1) {
      asm volatile("s_waitcnt vmcnt(6)" ::: "memory");
    } else {
      asm volatile("s_waitcnt vmcnt(0)" ::: "memory");
    }
    __builtin_amdgcn_s_barrier();
    // barrier proof: every wave passed ITS vmcnt -> all tile-t LDS writes done;
    // every wave finished iter t-1's ds_reads (lgkm deps precede its MFMAs)
    // -> buf[(t+2)%3] == buf[(t-1)%3] is free to overwrite below.

    const int cur = t % 3;
    const u16* lA = ldsA[cur];
    const u16* lB = ldsB[cur];

    bf16x8 af[2][2], bfv[2][4];
#pragma unroll
    for (int kk = 0; kk < 2; kk++) {
      const int slot = kk * 4 + lk;
#pragma unroll
      for (int m = 0; m < 2; m++) {
        const int R = wr * 32 + m * 16 + rl;
        af[kk][m] = *(const bf16x8*)(lA + R * BK + ((slot ^ (R & 7)) * 8));
      }
#pragma unroll
      for (int n = 0; n < 4; n++) {
        const int R = wc * 64 + n * 16 + rl;
        bfv[kk][n] = *(const bf16x8*)(lB + R * BK + ((slot ^ (R & 7)) * 8));
      }
    }

    if (t + 2 < NTILES) {  // stage tile t+2; stays in flight across next barrier
      const int k0 = (t + 2) * BK;
      const int nxt = (t + 2) % 3;
#pragma unroll
      for (int j = 0; j < 2; j++) gload_lds16(Abase + offA[j] + k0, &ldsA[nxt][ldA[j]]);
#pragma unroll
      for (int j = 0; j < 4; j++) gload_lds16(Bbase + offB[j] + k0, &ldsB[nxt][ldB[j]]);
    }

#pragma unroll
    for (int kk = 0; kk < 2; kk++)
#pragma unroll
      for (int m = 0; m < 2; m++)
#pragma unroll
        for (int n = 0; n < 4; n++)
          acc[m][n] = __builtin_amdgcn_mfma_f32_16x16x32_bf16(af[kk][m], bfv[kk][n], acc[m][n], 0, 0, 0);
  }

  // epilogue: C/D layout col = lane&15, row = (lane>>4)*4 + reg  [m89-verified]
  const int gr0 = by * BM + wr * 32;
  const int gc0 = bx * BN + wc * 64;
  const int rh = (lane >> 4) * 4;
  float bv[4];
#pragma unroll
  for (int n = 0; n < 4; n++) bv[n] = bias[gc0 + n * 16 + rl];
#pragma unroll
  for (int m = 0; m < 2; m++) {
#pragma unroll
    for (int n = 0; n < 4; n++) {
      const int col = gc0 + n * 16 + rl;
#pragma unroll
      for (int j = 0; j < 4; j++)
        out[(int64_t)(gr0 + m * 16 + rh + j) * OUT_F + col] = acc[m][n][j] + bv[n];
    }
  }
}

// ---------------- launch ----------------

extern "C" void kernel_launch(void* const* d_in, const int* in_sizes, int n_in,
                              void* d_out, int out_size, void* d_ws, size_t ws_size,
                              hipStream_t stream) {
  const float* x     = (const float*)d_in[0];
  const float* eps_w = (const float*)d_in[1];
  const float* eps_b = (const float*)d_in[2];
  const float* mu_w  = (const float*)d_in[3];
  const float* ls_w  = (const float*)d_in[4];
  const float* mu_b  = (const float*)d_in[5];
  const float* ls_b  = (const float*)d_in[6];
  float* out = (float*)d_out;

  u16* Wq = (u16*)d_ws;                              // 32 MB
  u16* Xq = Wq + (size_t)OUT_F * IN_F;               //  8 MB
  float* bq = (float*)(Xq + (size_t)BATCH * IN_F);   // 16 KB

  prep_kernel<<<PREP_GRID, 256, 0, stream>>>(mu_w, ls_w, eps_w, Wq,
                                             x, Xq, mu_b, ls_b, eps_b, bq);
  gemm_kernel<<<(BATCH / BM) * NBX, 256, 0, stream>>>(Xq, Wq, bq, out);
}